// Round 7
// baseline (355.005 us; speedup 1.0000x reference)
//
#include <hip/hip_runtime.h>
#include <math.h>

#define DIM 512
#define HEADS 8
#define QL 225
#define VS 196
#define BATCH 4
#define EPS_BN 1e-5f

typedef __attribute__((ext_vector_type(8))) short bf16x8;
typedef __attribute__((ext_vector_type(4))) float f32x4;

// ---------------- wave (64-lane) reductions ----------------
__device__ __forceinline__ float waveMax(float v) {
#pragma unroll
    for (int o = 32; o; o >>= 1) v = fmaxf(v, __shfl_xor(v, o, 64));
    return v;
}
__device__ __forceinline__ float waveSum(float v) {
#pragma unroll
    for (int o = 32; o; o >>= 1) v += __shfl_xor(v, o, 64);
    return v;
}

// ---------------- fp32 -> bf16 pack helpers ----------------
__device__ __forceinline__ unsigned cvt_pk_bf16(float lo, float hi) {
    unsigned r;
    asm("v_cvt_pk_bf16_f32 %0, %1, %2" : "=v"(r) : "v"(lo), "v"(hi));
    return r;
}
__device__ __forceinline__ uint4 ld_cvt8(const float* p) {
    float4 x = *(const float4*)p;
    float4 y = *(const float4*)(p + 4);
    uint4 r;
    r.x = cvt_pk_bf16(x.x, x.y);
    r.y = cvt_pk_bf16(x.z, x.w);
    r.z = cvt_pk_bf16(y.x, y.y);
    r.w = cvt_pk_bf16(y.z, y.w);
    return r;
}

// ---------------- multi-job bf16-MFMA GEMM (N=K=512): Out = scale*A@W^T (+bias)(relu)(+Add) ----
// Tile 64x64, BK=64, 4 waves in 2x2 (each 32x32 = 2x2 frags of 16x16x32).
struct GJob {
    const float* A; const float* W; const float* bias; const float* Add; float* Out;
    long aBS, aOff, addBS, addOff;
    int aRows, addRows, M, relu;
    float scale; int pad0, pad1, pad2;
};
struct GJobs { GJob j[4]; };

template<int LAYER>
__global__ __launch_bounds__(256) void gemm_multi(GJobs jobs) {
    const GJob J = jobs.j[blockIdx.z];
    const int bm = blockIdx.y * 64, bn = blockIdx.x * 64;
    if (bm >= J.M) return;
    __shared__ __align__(16) ushort As[64][72];
    __shared__ __align__(16) ushort Bs[64][72];
    const int tid = threadIdx.x;
    const int srow = tid >> 2, skq = tid & 3;   // staging: row 0..63, 16-k chunk
    const float* ap = nullptr;
    {
        int m = bm + srow;
        if (m < J.M) { int bb = m / J.aRows; int r = m - bb * J.aRows;
                       ap = J.A + bb * J.aBS + J.aOff + (long)r * 512 + skq * 16; }
    }
    const float* bp = J.W + (long)(bn + srow) * 512 + skq * 16;

    const int lane = tid & 63, wid = tid >> 6;
    const int wr = wid >> 1, wc = wid & 1;      // 2x2 wave grid of 32x32 tiles
    const int lr = lane & 15, kg = lane >> 4;

    f32x4 acc[2][2] = {};

    for (int kt = 0; kt < 512; kt += 64) {
        uint4 a01 = {0u,0u,0u,0u}, a23 = {0u,0u,0u,0u};
        if (ap) { a01 = ld_cvt8(ap + kt); a23 = ld_cvt8(ap + kt + 8); }
        uint4 b01 = ld_cvt8(bp + kt), b23 = ld_cvt8(bp + kt + 8);
        __syncthreads();
        *(uint4*)&As[srow][skq * 16]     = a01;
        *(uint4*)&As[srow][skq * 16 + 8] = a23;
        *(uint4*)&Bs[srow][skq * 16]     = b01;
        *(uint4*)&Bs[srow][skq * 16 + 8] = b23;
        __syncthreads();
        bf16x8 a[2][2], bb[2][2];
#pragma unroll
        for (int i = 0; i < 2; i++)
#pragma unroll
            for (int kf = 0; kf < 2; kf++)
                a[i][kf] = *(const bf16x8*)&As[wr * 32 + i * 16 + lr][kf * 32 + kg * 8];
#pragma unroll
        for (int j = 0; j < 2; j++)
#pragma unroll
            for (int kf = 0; kf < 2; kf++)
                bb[j][kf] = *(const bf16x8*)&Bs[wc * 32 + j * 16 + lr][kf * 32 + kg * 8];
#pragma unroll
        for (int i = 0; i < 2; i++)
#pragma unroll
            for (int j = 0; j < 2; j++) {
                acc[i][j] = __builtin_amdgcn_mfma_f32_16x16x32_bf16(a[i][0], bb[j][0], acc[i][j], 0, 0, 0);
                acc[i][j] = __builtin_amdgcn_mfma_f32_16x16x32_bf16(a[i][1], bb[j][1], acc[i][j], 0, 0, 0);
            }
    }

    // C/D layout: col = lane&15, row = (lane>>4)*4 + reg
#pragma unroll
    for (int i = 0; i < 2; i++) {
#pragma unroll
        for (int r = 0; r < 4; r++) {
            int m = bm + wr * 32 + i * 16 + kg * 4 + r;
            if (m >= J.M) continue;
            const float* addrow = nullptr;
            if (J.Add) {
                int bb2 = m / J.addRows; int rr = m - bb2 * J.addRows;
                addrow = J.Add + bb2 * J.addBS + J.addOff + (long)rr * 512;
            }
            float* orow = J.Out + (long)m * 512;
#pragma unroll
            for (int j = 0; j < 2; j++) {
                int n = bn + wc * 32 + j * 16 + lr;
                float v = acc[i][j][r] * J.scale;
                if (J.bias) v += J.bias[n];
                if (J.relu) v = fmaxf(v, 0.f);
                if (addrow) v += addrow[n];
                orow[n] = v;
            }
        }
    }
}

// ---------------- attention 1: P[b,h,n,q] = softmax_n( q[b,q,:]·k[b,n,:] ) (transposed store) ----
__global__ __launch_bounds__(256) void attn1_kernel(const float* __restrict__ qs,
                                                    const float* __restrict__ ks,
                                                    float* __restrict__ P) {
    int bid = blockIdx.x;
    int qi = bid % QL;
    int h = (bid / QL) % HEADS;
    int b = bid / (QL * HEADS);
    __shared__ __align__(16) float qrow[64];
    __shared__ float redm[4], reds[4];
    int tid = threadIdx.x;
    if (tid < 64) qrow[tid] = qs[((long)(b * QL + qi)) * DIM + h * 64 + tid];
    __syncthreads();
    float s = -1e30f;
    if (tid < VS) {
        const float4* kr4 = (const float4*)(ks + ((long)(b * VS + tid)) * DIM + h * 64);
        const float4* q4 = (const float4*)qrow;
        float acc = 0.f;
#pragma unroll
        for (int i = 0; i < 16; i++) {
            float4 kv = kr4[i], qv = q4[i];
            acc += qv.x * kv.x + qv.y * kv.y + qv.z * kv.z + qv.w * kv.w;
        }
        s = acc;
    }
    float wm = waveMax(s);
    if ((tid & 63) == 0) redm[tid >> 6] = wm;
    __syncthreads();
    float m = fmaxf(fmaxf(redm[0], redm[1]), fmaxf(redm[2], redm[3]));
    float e = (tid < VS) ? expf(s - m) : 0.f;
    float ws = waveSum(e);
    if ((tid & 63) == 0) reds[tid >> 6] = ws;
    __syncthreads();
    float tot = reds[0] + reds[1] + reds[2] + reds[3];
    if (tid < VS) P[(((long)(b * HEADS + h)) * VS + tid) * QL + qi] = e / tot;
}

// ---------------- fused: h = P*v -> dwconv1+bn1+relu -> dwconv2+bn2+relu -> mean over n ----
// v4: 4 planes per block (one per wave), lane owns 4 columns, n-range SPLIT 4-way
// across blocks (49 outputs each, 2-row pipeline warmup halo). Partial column sums
// combined via atomicAdd into zero-initialized m2. Grid 2048 -> full occupancy.
#define CSTEP4(N, HA,HAl,HAr, HB,HBl,HBr, HC,HCl,HCr, GA,GAl,GAr, GB,GBl,GBr, GC,GCl,GCr)      \
{                                                                                              \
    float4 pv = make_float4(0.f, 0.f, 0.f, 0.f);                                               \
    if ((N) >= 0 && (N) < VS) {                                                                \
        float vn = vcolw[wave][(N) - nbase];                                                   \
        const float* rp = Pp + (long)(N) * QL;                                                 \
        pv.x = rp[off0] * vn * mk0;                                                            \
        pv.y = rp[off1] * vn * mk1;                                                            \
        pv.z = rp[off2] * vn * mk2;                                                            \
        pv.w = rp[off3] * vn * mk3;                                                            \
    }                                                                                          \
    HC = pv;                                                                                   \
    HCl = __shfl_up(pv.w, 1, 64); if (lane == 0) HCl = 0.f;                                    \
    HCr = __shfl_down(pv.x, 1, 64);                                                            \
    float4 g = make_float4(0.f, 0.f, 0.f, 0.f);                                                \
    if ((N) >= 1 && (N) <= VS) {                                                               \
        g.x = w1s[0]*HAl  + w1s[1]*HA.x + w1s[2]*HA.y                                          \
            + w1s[3]*HBl  + w1s[4]*HB.x + w1s[5]*HB.y                                          \
            + w1s[6]*HCl  + w1s[7]*HC.x + w1s[8]*HC.y;                                         \
        g.y = w1s[0]*HA.x + w1s[1]*HA.y + w1s[2]*HA.z                                          \
            + w1s[3]*HB.x + w1s[4]*HB.y + w1s[5]*HB.z                                          \
            + w1s[6]*HC.x + w1s[7]*HC.y + w1s[8]*HC.z;                                         \
        g.z = w1s[0]*HA.y + w1s[1]*HA.z + w1s[2]*HA.w                                          \
            + w1s[3]*HB.y + w1s[4]*HB.z + w1s[5]*HB.w                                          \
            + w1s[6]*HC.y + w1s[7]*HC.z + w1s[8]*HC.w;                                         \
        g.w = w1s[0]*HA.z + w1s[1]*HA.w + w1s[2]*HAr                                           \
            + w1s[3]*HB.z + w1s[4]*HB.w + w1s[5]*HBr                                           \
            + w1s[6]*HC.z + w1s[7]*HC.w + w1s[8]*HCr;                                          \
        g.x = fmaxf(g.x * s1 + b1v, 0.f) * mk0;                                                \
        g.y = fmaxf(g.y * s1 + b1v, 0.f) * mk1;                                                \
        g.z = fmaxf(g.z * s1 + b1v, 0.f) * mk2;                                                \
        g.w = fmaxf(g.w * s1 + b1v, 0.f) * mk3;                                                \
    }                                                                                          \
    GC = g;                                                                                    \
    GCl = __shfl_up(g.w, 1, 64); if (lane == 0) GCl = 0.f;                                     \
    GCr = __shfl_down(g.x, 1, 64);                                                             \
    if ((N) >= lo + 2 && (N) < hi + 2) {                                                       \
        float t0 = w2s[0]*GAl  + w2s[1]*GA.x + w2s[2]*GA.y                                     \
                 + w2s[3]*GBl  + w2s[4]*GB.x + w2s[5]*GB.y                                     \
                 + w2s[6]*GCl  + w2s[7]*GC.x + w2s[8]*GC.y;                                    \
        float t1 = w2s[0]*GA.x + w2s[1]*GA.y + w2s[2]*GA.z                                     \
                 + w2s[3]*GB.x + w2s[4]*GB.y + w2s[5]*GB.z                                     \
                 + w2s[6]*GC.x + w2s[7]*GC.y + w2s[8]*GC.z;                                    \
        float t2 = w2s[0]*GA.y + w2s[1]*GA.z + w2s[2]*GA.w                                     \
                 + w2s[3]*GB.y + w2s[4]*GB.z + w2s[5]*GB.w                                     \
                 + w2s[6]*GC.y + w2s[7]*GC.z + w2s[8]*GC.w;                                    \
        float t3 = w2s[0]*GA.z + w2s[1]*GA.w + w2s[2]*GAr                                      \
                 + w2s[3]*GB.z + w2s[4]*GB.w + w2s[5]*GBr                                      \
                 + w2s[6]*GC.z + w2s[7]*GC.w + w2s[8]*GCr;                                     \
        csum.x += fmaxf(t0 * s2 + b2v, 0.f);                                                   \
        csum.y += fmaxf(t1 * s2 + b2v, 0.f);                                                   \
        csum.z += fmaxf(t2 * s2 + b2v, 0.f);                                                   \
        csum.w += fmaxf(t3 * s2 + b2v, 0.f);                                                   \
    }                                                                                          \
}

__global__ __launch_bounds__(256) void conv_fuse_kernel(
    const float* __restrict__ P, const float* __restrict__ vs,
    const float* __restrict__ dw1, const float* __restrict__ dw2,
    const float* __restrict__ bn1g, const float* __restrict__ bn1b,
    const float* __restrict__ bn1m, const float* __restrict__ bn1v,
    const float* __restrict__ bn2g, const float* __restrict__ bn2b,
    const float* __restrict__ bn2m, const float* __restrict__ bn2v,
    float* __restrict__ m2) {
    int bc = blockIdx.x;            // 2048 = 4 ns * 128 cq * 4 b
    int ns = bc & 3;
    int cq = ((bc >> 2) & 127) * 4;
    int b = bc >> 9;
    const int lo = ns * 49, hi = lo + 49;
    const int nbase = lo - 2;
    int tid = threadIdx.x;
    int wave = tid >> 6, lane = tid & 63;
    int c = cq + wave;
    int h = c >> 6;
    __shared__ float vcolw[4][64];
    {   // load only the 54-row slice this block streams
        int n = nbase + (tid >> 2);
        float v = 0.f;
        if (n >= 0 && n < VS) v = vs[((long)(b * VS + n)) * DIM + cq + (tid & 3)];
        vcolw[tid & 3][tid >> 2] = v;
    }
    float w1s[9], w2s[9];
#pragma unroll
    for (int i = 0; i < 9; i++) { w1s[i] = dw1[c * 9 + i]; w2s[i] = dw2[c * 9 + i]; }
    float s1 = bn1g[c] * rsqrtf(bn1v[c] + EPS_BN);
    float b1v = bn1b[c] - bn1m[c] * s1;
    float s2 = bn2g[c] * rsqrtf(bn2v[c] + EPS_BN);
    float b2v = bn2b[c] - bn2m[c] * s2;
    const float* Pp = P + ((long)(b * HEADS + h)) * VS * QL;
    int c0 = lane * 4;
    float mk0 = (c0 + 0 < QL) ? 1.f : 0.f;
    float mk1 = (c0 + 1 < QL) ? 1.f : 0.f;
    float mk2 = (c0 + 2 < QL) ? 1.f : 0.f;
    float mk3 = (c0 + 3 < QL) ? 1.f : 0.f;
    int off0 = min(c0 + 0, QL - 1), off1 = min(c0 + 1, QL - 1);
    int off2 = min(c0 + 2, QL - 1), off3 = min(c0 + 3, QL - 1);
    __syncthreads();
    float4 hA = make_float4(0,0,0,0), hB = hA, hC = hA;
    float hAl = 0, hAr = 0, hBl = 0, hBr = 0, hCl = 0, hCr = 0;
    float4 gA = make_float4(0,0,0,0), gB = gA, gC = gA;
    float gAl = 0, gAr = 0, gBl = 0, gBr = 0, gCl = 0, gCr = 0;
    float4 csum = make_float4(0,0,0,0);
    // 54 steps (warmup 2 + 49 outputs + tail), 3-phase register rotation
#pragma unroll 6
    for (int s = 0; s < 54; s += 3) {
        int N0 = nbase + s;
        CSTEP4(N0,     hA,hAl,hAr, hB,hBl,hBr, hC,hCl,hCr, gA,gAl,gAr, gB,gBl,gBr, gC,gCl,gCr)
        CSTEP4(N0 + 1, hB,hBl,hBr, hC,hCl,hCr, hA,hAl,hAr, gB,gBl,gBr, gC,gCl,gCr, gA,gAl,gAr)
        CSTEP4(N0 + 2, hC,hCl,hCr, hA,hAl,hAr, hB,hBl,hBr, gC,gCl,gCr, gA,gAl,gAr, gB,gBl,gBr)
    }
    const float inv = 1.f / (float)VS;
    if (c0 + 0 < QL) atomicAdd(&m2[((long)(b * QL + c0 + 0)) * DIM + c], csum.x * inv);
    if (c0 + 1 < QL) atomicAdd(&m2[((long)(b * QL + c0 + 1)) * DIM + c], csum.y * inv);
    if (c0 + 2 < QL) atomicAdd(&m2[((long)(b * QL + c0 + 2)) * DIM + c], csum.z * inv);
    if (c0 + 3 < QL) atomicAdd(&m2[((long)(b * QL + c0 + 3)) * DIM + c], csum.w * inv);
}

// ---------------- attention 2: O[b,n,:] = Qm[b,n,:] + softmax_q(Qm·Km/sqrt(512)) @ Vm ----
__global__ __launch_bounds__(256) void attn2_kernel(const float* __restrict__ Qm,
                                                    const float* __restrict__ Km,
                                                    const float* __restrict__ Vm,
                                                    float* __restrict__ O) {
    int bid = blockIdx.x;
    int n = bid % VS;
    int h = (bid / VS) % HEADS;
    int b = bid / (VS * HEADS);
    __shared__ __align__(16) float qrow[64];
    __shared__ float av[QL];
    __shared__ __align__(16) float4 red4[16][16];
    __shared__ float redm[4], reds[4];
    int tid = threadIdx.x;
    if (tid < 64) qrow[tid] = Qm[((long)(b * VS + n)) * DIM + h * 64 + tid];
    __syncthreads();
    float s = -1e30f;
    if (tid < QL) {
        const float4* kr4 = (const float4*)(Km + ((long)(b * QL + tid)) * DIM + h * 64);
        const float4* q4 = (const float4*)qrow;
        float acc = 0.f;
#pragma unroll
        for (int i = 0; i < 16; i++) {
            float4 kv = kr4[i], qv = q4[i];
            acc += qv.x * kv.x + qv.y * kv.y + qv.z * kv.z + qv.w * kv.w;
        }
        s = acc * 0.044194173824159216f; // 1/sqrt(512)
    }
    float wm = waveMax(s);
    if ((tid & 63) == 0) redm[tid >> 6] = wm;
    __syncthreads();
    float m = fmaxf(fmaxf(redm[0], redm[1]), fmaxf(redm[2], redm[3]));
    float e = (tid < QL) ? expf(s - m) : 0.f;
    float ws = waveSum(e);
    if ((tid & 63) == 0) reds[tid >> 6] = ws;
    __syncthreads();
    float tot = reds[0] + reds[1] + reds[2] + reds[3];
    if (tid < QL) av[tid] = e / tot;
    __syncthreads();
    int qp = tid >> 4, dq = tid & 15;
    float4 acc4 = make_float4(0, 0, 0, 0);
    for (int it = 0; it < 15; it++) {
        int qq = it * 16 + qp;
        if (qq < QL) {
            float a = av[qq];
            float4 v4 = *(const float4*)(Vm + ((long)(b * QL + qq)) * DIM + h * 64 + dq * 4);
            acc4.x += a * v4.x; acc4.y += a * v4.y; acc4.z += a * v4.z; acc4.w += a * v4.w;
        }
    }
    red4[qp][dq] = acc4;
    __syncthreads();
#pragma unroll
    for (int st = 8; st >= 1; st >>= 1) {
        if (qp < st) {
            float4 o = red4[qp + st][dq];
            acc4.x += o.x; acc4.y += o.y; acc4.z += o.z; acc4.w += o.w;
            red4[qp][dq] = acc4;
        }
        __syncthreads();
    }
    if (tid < 16) {
        float4 r = red4[0][tid];
        float4 qv = ((const float4*)qrow)[tid];
        float4 o = make_float4(qv.x + r.x, qv.y + r.y, qv.z + r.z, qv.w + r.w);
        *(float4*)(O + ((long)(b * VS + n)) * DIM + h * 64 + tid * 4) = o;
    }
}

static inline GJob mkjob(const float* A, int aRows, long aBS, long aOff,
                         const float* W, const float* bias,
                         const float* Add, int addRows, long addBS, long addOff,
                         float* Out, int M, float scale, int relu) {
    GJob j;
    j.A = A; j.W = W; j.bias = bias; j.Add = Add; j.Out = Out;
    j.aBS = aBS; j.aOff = aOff; j.addBS = addBS; j.addOff = addOff;
    j.aRows = aRows; j.addRows = addRows; j.M = M; j.relu = relu;
    j.scale = scale; j.pad0 = j.pad1 = j.pad2 = 0;
    return j;
}

extern "C" void kernel_launch(void* const* d_in, const int* in_sizes, int n_in,
                              void* d_out, int out_size, void* d_ws, size_t ws_size,
                              hipStream_t stream) {
    const float* x     = (const float*)d_in[0];
    const float* Wq    = (const float*)d_in[1];
    const float* Wk    = (const float*)d_in[2];
    const float* Wv    = (const float*)d_in[3];
    const float* Wproj = (const float*)d_in[4];
    const float* bproj = (const float*)d_in[5];
    const float* dw1   = (const float*)d_in[6];
    const float* dw2   = (const float*)d_in[7];
    const float* pw    = (const float*)d_in[8];
    const float* bn1g  = (const float*)d_in[9];
    const float* bn1b  = (const float*)d_in[10];
    const float* bn1m  = (const float*)d_in[11];
    const float* bn1v  = (const float*)d_in[12];
    const float* bn2g  = (const float*)d_in[13];
    const float* bn2b  = (const float*)d_in[14];
    const float* bn2m  = (const float*)d_in[15];
    const float* bn2v  = (const float*)d_in[16];
    const float* mWq   = (const float*)d_in[17];
    const float* mbq   = (const float*)d_in[18];
    const float* mWk   = (const float*)d_in[19];
    const float* mbk   = (const float*)d_in[20];
    const float* mWv   = (const float*)d_in[21];
    const float* mbv   = (const float*)d_in[22];
    const float* mWo   = (const float*)d_in[23];
    const float* mbo   = (const float*)d_in[24];

    float* ws = (float*)d_ws;
    // Overlay (floats):
    //   qs @ 0 (460800) -> m2 -> Km
    //   ks @ 460800 (401408) -> O
    //   vsb @ 862208 (401408) -> O2
    //   P @ 1263616 (1411200) -> [kc @ +0 | Qm @ +460800 | Vm @ +862208]
    float* qs = ws;
    float* ks = ws + 460800;
    float* vsb = ws + 862208;
    float* P  = ws + 1263616;
    float* m2 = ws;
    float* kc = ws + 1263616;
    float* Qm = ws + 1263616 + 460800;
    float* Vm = ws + 1263616 + 460800 + 401408;
    float* Km = ws;
    float* O  = ws + 460800;
    float* O2 = ws + 862208;

    const long xBS = 421L * DIM;
    const long clsOff = 196L * DIM;

    dim3 blk(256);

    // L1: q,k,v projections fused (360 blocks)
    {
        GJobs js;
        js.j[0] = mkjob(x, QL, xBS, clsOff, Wq, nullptr, nullptr, 1, 0, 0, qs, 900, 0.125f, 0);
        js.j[1] = mkjob(x, VS, xBS, 0, Wk, nullptr, nullptr, 1, 0, 0, ks, 784, 1.f, 0);
        js.j[2] = mkjob(x, VS, xBS, 0, Wv, nullptr, nullptr, 1, 0, 0, vsb, 784, 1.f, 0);
        js.j[3] = js.j[0];
        gemm_multi<0><<<dim3(8, 15, 3), blk, 0, stream>>>(js);
    }
    attn1_kernel<<<BATCH * HEADS * QL, blk, 0, stream>>>(qs, ks, P);
    // zero m2 (qs region is dead after attn1); conv accumulates into it atomically
    hipMemsetAsync(m2, 0, 460800 * sizeof(float), stream);
    conv_fuse_kernel<<<2048, blk, 0, stream>>>(P, vsb, dw1, dw2,
                                               bn1g, bn1b, bn1m, bn1v,
                                               bn2g, bn2b, bn2m, bn2v, m2);
    // L2: kc = cls_cat + m2 @ pw^T  AND  Qm = x_sem @ mWq^T + mbq   (P dead now)
    {
        GJobs js;
        js.j[0] = mkjob(m2, 900, 0, 0, pw, nullptr, x, QL, xBS, clsOff, kc, 900, 1.f, 0);
        js.j[1] = mkjob(x, VS, xBS, 0, mWq, mbq, nullptr, 1, 0, 0, Qm, 784, 1.f, 0);
        js.j[2] = js.j[3] = js.j[0];
        gemm_multi<1><<<dim3(8, 15, 2), blk, 0, stream>>>(js);
    }
    // L3: Km, Vm off kc
    {
        GJobs js;
        js.j[0] = mkjob(kc, 900, 0, 0, mWk, mbk, nullptr, 1, 0, 0, Km, 900, 1.f, 0);
        js.j[1] = mkjob(kc, 900, 0, 0, mWv, mbv, nullptr, 1, 0, 0, Vm, 900, 1.f, 0);
        js.j[2] = js.j[3] = js.j[0];
        gemm_multi<2><<<dim3(8, 15, 2), blk, 0, stream>>>(js);
    }
    attn2_kernel<<<BATCH * HEADS * VS, blk, 0, stream>>>(Qm, Km, Vm, O);
    // L4: O2 = O + relu(O @ mWo^T + mbo)
    {
        GJobs js;
        js.j[0] = mkjob(O, 784, 0, 0, mWo, mbo, O, 784, 0, 0, O2, 784, 1.f, 1);
        js.j[1] = js.j[2] = js.j[3] = js.j[0];
        gemm_multi<3><<<dim3(8, 13, 1), blk, 0, stream>>>(js);
    }
    // L5: out = O2 @ Wproj^T + bproj
    {
        GJobs js;
        js.j[0] = mkjob(O2, 784, 0, 0, Wproj, bproj, nullptr, 1, 0, 0, (float*)d_out, 784, 1.f, 0);
        js.j[1] = js.j[2] = js.j[3] = js.j[0];
        gemm_multi<4><<<dim3(8, 13, 1), blk, 0, stream>>>(js);
    }
}

// Round 8
// 288.834 us; speedup vs baseline: 1.2291x; 1.2291x over previous
//
#include <hip/hip_runtime.h>
#include <math.h>

#define DIM 512
#define HEADS 8
#define QL 225
#define VS 196
#define BATCH 4
#define EPS_BN 1e-5f

typedef __attribute__((ext_vector_type(8))) short bf16x8;
typedef __attribute__((ext_vector_type(4))) float f32x4;

// ---------------- wave (64-lane) reductions ----------------
__device__ __forceinline__ float waveMax(float v) {
#pragma unroll
    for (int o = 32; o; o >>= 1) v = fmaxf(v, __shfl_xor(v, o, 64));
    return v;
}
__device__ __forceinline__ float waveSum(float v) {
#pragma unroll
    for (int o = 32; o; o >>= 1) v += __shfl_xor(v, o, 64);
    return v;
}

// ---------------- fp32 -> bf16 pack helpers ----------------
__device__ __forceinline__ unsigned cvt_pk_bf16(float lo, float hi) {
    unsigned r;
    asm("v_cvt_pk_bf16_f32 %0, %1, %2" : "=v"(r) : "v"(lo), "v"(hi));
    return r;
}
__device__ __forceinline__ uint4 ld_cvt8(const float* p) {
    float4 x = *(const float4*)p;
    float4 y = *(const float4*)(p + 4);
    uint4 r;
    r.x = cvt_pk_bf16(x.x, x.y);
    r.y = cvt_pk_bf16(x.z, x.w);
    r.z = cvt_pk_bf16(y.x, y.y);
    r.w = cvt_pk_bf16(y.z, y.w);
    return r;
}

// ---------------- multi-job bf16-MFMA GEMM (N=K=512): Out = scale*A@W^T (+bias)(relu)(+Add) ----
// Tile 64x64, BK=64, 4 waves in 2x2 (each 32x32). Software-pipelined: iteration
// k+1's global loads issue BEFORE iteration k's MFMA so load latency overlaps compute.
struct GJob {
    const float* A; const float* W; const float* bias; const float* Add; float* Out;
    long aBS, aOff, addBS, addOff;
    int aRows, addRows, M, relu;
    float scale; int pad0, pad1, pad2;
};
struct GJobs { GJob j[4]; };

template<int LAYER>
__global__ __launch_bounds__(256) void gemm_multi(GJobs jobs) {
    const GJob J = jobs.j[blockIdx.z];
    const int bm = blockIdx.y * 64, bn = blockIdx.x * 64;
    if (bm >= J.M) return;
    __shared__ __align__(16) ushort As[64][72];
    __shared__ __align__(16) ushort Bs[64][72];
    const int tid = threadIdx.x;
    const int srow = tid >> 2, skq = tid & 3;   // staging: row 0..63, 16-k chunk
    const float* ap = nullptr;
    {
        int m = bm + srow;
        if (m < J.M) { int bb = m / J.aRows; int r = m - bb * J.aRows;
                       ap = J.A + bb * J.aBS + J.aOff + (long)r * 512 + skq * 16; }
    }
    const float* bp = J.W + (long)(bn + srow) * 512 + skq * 16;

    const int lane = tid & 63, wid = tid >> 6;
    const int wr = wid >> 1, wc = wid & 1;      // 2x2 wave grid of 32x32 tiles
    const int lr = lane & 15, kg = lane >> 4;

    f32x4 acc[2][2] = {};

    // preload kt = 0
    uint4 a01 = {0u,0u,0u,0u}, a23 = {0u,0u,0u,0u};
    if (ap) { a01 = ld_cvt8(ap); a23 = ld_cvt8(ap + 8); }
    uint4 b01 = ld_cvt8(bp), b23 = ld_cvt8(bp + 8);

    for (int kt = 0; kt < 512; kt += 64) {
        __syncthreads();            // previous iteration's frag reads done
        *(uint4*)&As[srow][skq * 16]     = a01;
        *(uint4*)&As[srow][skq * 16 + 8] = a23;
        *(uint4*)&Bs[srow][skq * 16]     = b01;
        *(uint4*)&Bs[srow][skq * 16 + 8] = b23;
        __syncthreads();            // tile visible
        // issue next iteration's loads early (overlap with MFMA below)
        if (kt + 64 < 512) {
            if (ap) { a01 = ld_cvt8(ap + kt + 64); a23 = ld_cvt8(ap + kt + 72); }
            b01 = ld_cvt8(bp + kt + 64); b23 = ld_cvt8(bp + kt + 72);
        }
        bf16x8 a[2][2], bb[2][2];
#pragma unroll
        for (int i = 0; i < 2; i++)
#pragma unroll
            for (int kf = 0; kf < 2; kf++)
                a[i][kf] = *(const bf16x8*)&As[wr * 32 + i * 16 + lr][kf * 32 + kg * 8];
#pragma unroll
        for (int j = 0; j < 2; j++)
#pragma unroll
            for (int kf = 0; kf < 2; kf++)
                bb[j][kf] = *(const bf16x8*)&Bs[wc * 32 + j * 16 + lr][kf * 32 + kg * 8];
#pragma unroll
        for (int i = 0; i < 2; i++)
#pragma unroll
            for (int j = 0; j < 2; j++) {
                acc[i][j] = __builtin_amdgcn_mfma_f32_16x16x32_bf16(a[i][0], bb[j][0], acc[i][j], 0, 0, 0);
                acc[i][j] = __builtin_amdgcn_mfma_f32_16x16x32_bf16(a[i][1], bb[j][1], acc[i][j], 0, 0, 0);
            }
    }

    // C/D layout: col = lane&15, row = (lane>>4)*4 + reg
#pragma unroll
    for (int i = 0; i < 2; i++) {
#pragma unroll
        for (int r = 0; r < 4; r++) {
            int m = bm + wr * 32 + i * 16 + kg * 4 + r;
            if (m >= J.M) continue;
            const float* addrow = nullptr;
            if (J.Add) {
                int bb2 = m / J.addRows; int rr = m - bb2 * J.addRows;
                addrow = J.Add + bb2 * J.addBS + J.addOff + (long)rr * 512;
            }
            float* orow = J.Out + (long)m * 512;
#pragma unroll
            for (int j = 0; j < 2; j++) {
                int n = bn + wc * 32 + j * 16 + lr;
                float v = acc[i][j][r] * J.scale;
                if (J.bias) v += J.bias[n];
                if (J.relu) v = fmaxf(v, 0.f);
                if (addrow) v += addrow[n];
                orow[n] = v;
            }
        }
    }
}

// ---------------- attention 1: P[b,h,n,q] = softmax_n( q[b,q,:]·k[b,n,:] ) (transposed store) ----
__global__ __launch_bounds__(256) void attn1_kernel(const float* __restrict__ qs,
                                                    const float* __restrict__ ks,
                                                    float* __restrict__ P) {
    int bid = blockIdx.x;
    int qi = bid % QL;
    int h = (bid / QL) % HEADS;
    int b = bid / (QL * HEADS);
    __shared__ __align__(16) float qrow[64];
    __shared__ float redm[4], reds[4];
    int tid = threadIdx.x;
    if (tid < 64) qrow[tid] = qs[((long)(b * QL + qi)) * DIM + h * 64 + tid];
    __syncthreads();
    float s = -1e30f;
    if (tid < VS) {
        const float4* kr4 = (const float4*)(ks + ((long)(b * VS + tid)) * DIM + h * 64);
        const float4* q4 = (const float4*)qrow;
        float acc = 0.f;
#pragma unroll
        for (int i = 0; i < 16; i++) {
            float4 kv = kr4[i], qv = q4[i];
            acc += qv.x * kv.x + qv.y * kv.y + qv.z * kv.z + qv.w * kv.w;
        }
        s = acc;
    }
    float wm = waveMax(s);
    if ((tid & 63) == 0) redm[tid >> 6] = wm;
    __syncthreads();
    float m = fmaxf(fmaxf(redm[0], redm[1]), fmaxf(redm[2], redm[3]));
    float e = (tid < VS) ? expf(s - m) : 0.f;
    float ws = waveSum(e);
    if ((tid & 63) == 0) reds[tid >> 6] = ws;
    __syncthreads();
    float tot = reds[0] + reds[1] + reds[2] + reds[3];
    if (tid < VS) P[(((long)(b * HEADS + h)) * VS + tid) * QL + qi] = e / tot;
}

// ---------------- fused: h = P*v -> dwconv1+bn1+relu -> dwconv2+bn2+relu -> mean over n ----
// v2 (proven 124us): one block per (b,c) plane, 4 waves; wave w owns output cols
// [w*60, w*60+59]; lane -> q = w*60 + lane - 2 (lanes 0,1,62,63 halo). Rolling
// 3-row register windows, shfl for horizontal taps. No LDS tiles, no main-loop barriers.
#define CSTEP(N, HAm,HAc,HAp, HBm,HBc,HBp, HCm,HCc,HCp, GAm,GAc,GAp, GBm,GBc,GBp, GCm,GCc,GCp) \
{                                                                                             \
    float pv = 0.f;                                                                           \
    if ((N) < VS) {                                                                           \
        float vn = vcol[(N)];                                                                 \
        if (qload) pv = Pp[(long)(N) * QL + q] * vn;                                          \
    }                                                                                         \
    HCc = pv;                                                                                 \
    HCm = __shfl_up(pv, 1, 64);                                                               \
    HCp = __shfl_down(pv, 1, 64);                                                             \
    float g = 0.f;                                                                            \
    if (gok && (N) >= 1 && (N) <= VS) {                                                       \
        float a1 = w1s[0]*HAm + w1s[1]*HAc + w1s[2]*HAp                                       \
                 + w1s[3]*HBm + w1s[4]*HBc + w1s[5]*HBp                                       \
                 + w1s[6]*HCm + w1s[7]*HCc + w1s[8]*HCp;                                      \
        g = fmaxf(a1 * s1 + b1v, 0.f);                                                        \
    }                                                                                         \
    GCc = g;                                                                                  \
    GCm = __shfl_up(g, 1, 64);                                                                \
    GCp = __shfl_down(g, 1, 64);                                                              \
    if ((N) >= 2) {                                                                           \
        float a2 = w2s[0]*GAm + w2s[1]*GAc + w2s[2]*GAp                                       \
                 + w2s[3]*GBm + w2s[4]*GBc + w2s[5]*GBp                                       \
                 + w2s[6]*GCm + w2s[7]*GCc + w2s[8]*GCp;                                      \
        csum += fmaxf(a2 * s2 + b2v, 0.f);                                                    \
    }                                                                                         \
}

__global__ __launch_bounds__(256) void conv_fuse_kernel(
    const float* __restrict__ P, const float* __restrict__ vs,
    const float* __restrict__ dw1, const float* __restrict__ dw2,
    const float* __restrict__ bn1g, const float* __restrict__ bn1b,
    const float* __restrict__ bn1m, const float* __restrict__ bn1v,
    const float* __restrict__ bn2g, const float* __restrict__ bn2b,
    const float* __restrict__ bn2m, const float* __restrict__ bn2v,
    float* __restrict__ m2) {
    int bc = blockIdx.x;
    int c = bc & (DIM - 1);
    int b = bc >> 9;
    int h = c >> 6;
    int tid = threadIdx.x;
    int wave = tid >> 6, lane = tid & 63;
    int q = wave * 60 + lane - 2;
    bool qload = (q >= 0 && q < QL);
    bool gok = (lane >= 1 && lane <= 62 && q >= 0 && q < QL);
    bool outok = (lane >= 2 && lane <= 61 && q < QL);
    __shared__ float vcol[VS];
    if (tid < VS) vcol[tid] = vs[((long)(b * VS + tid)) * DIM + c];
    float w1s[9], w2s[9];
#pragma unroll
    for (int i = 0; i < 9; i++) { w1s[i] = dw1[c * 9 + i]; w2s[i] = dw2[c * 9 + i]; }
    float s1 = bn1g[c] * rsqrtf(bn1v[c] + EPS_BN);
    float b1v = bn1b[c] - bn1m[c] * s1;
    float s2 = bn2g[c] * rsqrtf(bn2v[c] + EPS_BN);
    float b2v = bn2b[c] - bn2m[c] * s2;
    const float* Pp = P + ((long)(b * HEADS + h)) * VS * QL;
    __syncthreads();
    float HAm = 0, HAc = 0, HAp = 0, HBm = 0, HBc = 0, HBp = 0, HCm = 0, HCc = 0, HCp = 0;
    float GAm = 0, GAc = 0, GAp = 0, GBm = 0, GBc = 0, GBp = 0, GCm = 0, GCc = 0, GCp = 0;
    float csum = 0.f;
    for (int nb = 0; nb < 198; nb += 3) {
        CSTEP(nb,     HAm,HAc,HAp, HBm,HBc,HBp, HCm,HCc,HCp, GAm,GAc,GAp, GBm,GBc,GBp, GCm,GCc,GCp)
        CSTEP(nb + 1, HBm,HBc,HBp, HCm,HCc,HCp, HAm,HAc,HAp, GBm,GBc,GBp, GCm,GCc,GCp, GAm,GAc,GAp)
        CSTEP(nb + 2, HCm,HCc,HCp, HAm,HAc,HAp, HBm,HBc,HBp, GCm,GCc,GCp, GAm,GAc,GAp, GBm,GBc,GBp)
    }
    if (outok) m2[((long)(b * QL + q)) * DIM + c] = csum * (1.f / (float)VS);
}

// ---------------- attention 2: O[b,n,:] = Qm[b,n,:] + softmax_q(Qm·Km/sqrt(512)) @ Vm ----
__global__ __launch_bounds__(256) void attn2_kernel(const float* __restrict__ Qm,
                                                    const float* __restrict__ Km,
                                                    const float* __restrict__ Vm,
                                                    float* __restrict__ O) {
    int bid = blockIdx.x;
    int n = bid % VS;
    int h = (bid / VS) % HEADS;
    int b = bid / (VS * HEADS);
    __shared__ __align__(16) float qrow[64];
    __shared__ float av[QL];
    __shared__ __align__(16) float4 red4[16][16];
    __shared__ float redm[4], reds[4];
    int tid = threadIdx.x;
    if (tid < 64) qrow[tid] = Qm[((long)(b * VS + n)) * DIM + h * 64 + tid];
    __syncthreads();
    float s = -1e30f;
    if (tid < QL) {
        const float4* kr4 = (const float4*)(Km + ((long)(b * QL + tid)) * DIM + h * 64);
        const float4* q4 = (const float4*)qrow;
        float acc = 0.f;
#pragma unroll
        for (int i = 0; i < 16; i++) {
            float4 kv = kr4[i], qv = q4[i];
            acc += qv.x * kv.x + qv.y * kv.y + qv.z * kv.z + qv.w * kv.w;
        }
        s = acc * 0.044194173824159216f; // 1/sqrt(512)
    }
    float wm = waveMax(s);
    if ((tid & 63) == 0) redm[tid >> 6] = wm;
    __syncthreads();
    float m = fmaxf(fmaxf(redm[0], redm[1]), fmaxf(redm[2], redm[3]));
    float e = (tid < QL) ? expf(s - m) : 0.f;
    float ws = waveSum(e);
    if ((tid & 63) == 0) reds[tid >> 6] = ws;
    __syncthreads();
    float tot = reds[0] + reds[1] + reds[2] + reds[3];
    if (tid < QL) av[tid] = e / tot;
    __syncthreads();
    int qp = tid >> 4, dq = tid & 15;
    float4 acc4 = make_float4(0, 0, 0, 0);
    for (int it = 0; it < 15; it++) {
        int qq = it * 16 + qp;
        if (qq < QL) {
            float a = av[qq];
            float4 v4 = *(const float4*)(Vm + ((long)(b * QL + qq)) * DIM + h * 64 + dq * 4);
            acc4.x += a * v4.x; acc4.y += a * v4.y; acc4.z += a * v4.z; acc4.w += a * v4.w;
        }
    }
    red4[qp][dq] = acc4;
    __syncthreads();
#pragma unroll
    for (int st = 8; st >= 1; st >>= 1) {
        if (qp < st) {
            float4 o = red4[qp + st][dq];
            acc4.x += o.x; acc4.y += o.y; acc4.z += o.z; acc4.w += o.w;
            red4[qp][dq] = acc4;
        }
        __syncthreads();
    }
    if (tid < 16) {
        float4 r = red4[0][tid];
        float4 qv = ((const float4*)qrow)[tid];
        float4 o = make_float4(qv.x + r.x, qv.y + r.y, qv.z + r.z, qv.w + r.w);
        *(float4*)(O + ((long)(b * VS + n)) * DIM + h * 64 + tid * 4) = o;
    }
}

static inline GJob mkjob(const float* A, int aRows, long aBS, long aOff,
                         const float* W, const float* bias,
                         const float* Add, int addRows, long addBS, long addOff,
                         float* Out, int M, float scale, int relu) {
    GJob j;
    j.A = A; j.W = W; j.bias = bias; j.Add = Add; j.Out = Out;
    j.aBS = aBS; j.aOff = aOff; j.addBS = addBS; j.addOff = addOff;
    j.aRows = aRows; j.addRows = addRows; j.M = M; j.relu = relu;
    j.scale = scale; j.pad0 = j.pad1 = j.pad2 = 0;
    return j;
}

extern "C" void kernel_launch(void* const* d_in, const int* in_sizes, int n_in,
                              void* d_out, int out_size, void* d_ws, size_t ws_size,
                              hipStream_t stream) {
    const float* x     = (const float*)d_in[0];
    const float* Wq    = (const float*)d_in[1];
    const float* Wk    = (const float*)d_in[2];
    const float* Wv    = (const float*)d_in[3];
    const float* Wproj = (const float*)d_in[4];
    const float* bproj = (const float*)d_in[5];
    const float* dw1   = (const float*)d_in[6];
    const float* dw2   = (const float*)d_in[7];
    const float* pw    = (const float*)d_in[8];
    const float* bn1g  = (const float*)d_in[9];
    const float* bn1b  = (const float*)d_in[10];
    const float* bn1m  = (const float*)d_in[11];
    const float* bn1v  = (const float*)d_in[12];
    const float* bn2g  = (const float*)d_in[13];
    const float* bn2b  = (const float*)d_in[14];
    const float* bn2m  = (const float*)d_in[15];
    const float* bn2v  = (const float*)d_in[16];
    const float* mWq   = (const float*)d_in[17];
    const float* mbq   = (const float*)d_in[18];
    const float* mWk   = (const float*)d_in[19];
    const float* mbk   = (const float*)d_in[20];
    const float* mWv   = (const float*)d_in[21];
    const float* mbv   = (const float*)d_in[22];
    const float* mWo   = (const float*)d_in[23];
    const float* mbo   = (const float*)d_in[24];

    float* ws = (float*)d_ws;
    // Overlay (floats):
    //   qs @ 0 (460800) -> m2 -> Km
    //   ks @ 460800 (401408) -> O
    //   vsb @ 862208 (401408) -> O2
    //   P @ 1263616 (1411200) -> [kc @ +0 | Qm @ +460800 | Vm @ +862208]
    float* qs = ws;
    float* ks = ws + 460800;
    float* vsb = ws + 862208;
    float* P  = ws + 1263616;
    float* m2 = ws;
    float* kc = ws + 1263616;
    float* Qm = ws + 1263616 + 460800;
    float* Vm = ws + 1263616 + 460800 + 401408;
    float* Km = ws;
    float* O  = ws + 460800;
    float* O2 = ws + 862208;

    const long xBS = 421L * DIM;
    const long clsOff = 196L * DIM;

    dim3 blk(256);

    // L1: q,k,v projections fused (360 blocks)
    {
        GJobs js;
        js.j[0] = mkjob(x, QL, xBS, clsOff, Wq, nullptr, nullptr, 1, 0, 0, qs, 900, 0.125f, 0);
        js.j[1] = mkjob(x, VS, xBS, 0, Wk, nullptr, nullptr, 1, 0, 0, ks, 784, 1.f, 0);
        js.j[2] = mkjob(x, VS, xBS, 0, Wv, nullptr, nullptr, 1, 0, 0, vsb, 784, 1.f, 0);
        js.j[3] = js.j[0];
        gemm_multi<0><<<dim3(8, 15, 3), blk, 0, stream>>>(js);
    }
    attn1_kernel<<<BATCH * HEADS * QL, blk, 0, stream>>>(qs, ks, P);
    conv_fuse_kernel<<<BATCH * DIM, blk, 0, stream>>>(P, vsb, dw1, dw2,
                                                      bn1g, bn1b, bn1m, bn1v,
                                                      bn2g, bn2b, bn2m, bn2v, m2);
    // L2: kc = cls_cat + m2 @ pw^T  AND  Qm = x_sem @ mWq^T + mbq   (P dead now)
    {
        GJobs js;
        js.j[0] = mkjob(m2, 900, 0, 0, pw, nullptr, x, QL, xBS, clsOff, kc, 900, 1.f, 0);
        js.j[1] = mkjob(x, VS, xBS, 0, mWq, mbq, nullptr, 1, 0, 0, Qm, 784, 1.f, 0);
        js.j[2] = js.j[3] = js.j[0];
        gemm_multi<1><<<dim3(8, 15, 2), blk, 0, stream>>>(js);
    }
    // L3: Km, Vm off kc
    {
        GJobs js;
        js.j[0] = mkjob(kc, 900, 0, 0, mWk, mbk, nullptr, 1, 0, 0, Km, 900, 1.f, 0);
        js.j[1] = mkjob(kc, 900, 0, 0, mWv, mbv, nullptr, 1, 0, 0, Vm, 900, 1.f, 0);
        js.j[2] = js.j[3] = js.j[0];
        gemm_multi<2><<<dim3(8, 15, 2), blk, 0, stream>>>(js);
    }
    attn2_kernel<<<BATCH * HEADS * VS, blk, 0, stream>>>(Qm, Km, Vm, O);
    // L4: O2 = O + relu(O @ mWo^T + mbo)
    {
        GJobs js;
        js.j[0] = mkjob(O, 784, 0, 0, mWo, mbo, O, 784, 0, 0, O2, 784, 1.f, 1);
        js.j[1] = js.j[2] = js.j[3] = js.j[0];
        gemm_multi<3><<<dim3(8, 13, 1), blk, 0, stream>>>(js);
    }
    // L5: out = O2 @ Wproj^T + bproj
    {
        GJobs js;
        js.j[0] = mkjob(O2, 784, 0, 0, Wproj, bproj, nullptr, 1, 0, 0, (float*)d_out, 784, 1.f, 0);
        js.j[1] = js.j[2] = js.j[3] = js.j[0];
        gemm_multi<4><<<dim3(8, 13, 1), blk, 0, stream>>>(js);
    }
}